// Round 1
// baseline (13454.749 us; speedup 1.0000x reference)
//
#include <hip/hip_runtime.h>
#include <cstddef>

// BiTreeLSTM forward, fp32 baseline.
// DEPTH=17, N_NODES=131071, FEAT=512, H=512.
//
// ws layout (floats):
//   [0)                      c_all   : N_NODES*512        (cell state per node)
//   [c_all end)              Bt      : 1024*3072          (transposed combined weights)
//   [Bt end)                 biasC   : 3072               (combined biases)
// Total ~281 MB.
//
// Bt columns: c in [0,512)   -> px unit c      (k>=512 rows are 0)
//             c in [512,3072)-> gate unit q=c-512 ; rows k<512 from iofux_w,
//                               rows k>=512 from iofuh_w.
// biasC[c]: c<512 -> px_b[c]; else iofux_b[q]+iofuh_b[q].

#define DEPTH 17
#define N_NODES ((1 << DEPTH) - 1)
#define FEAT 512
#define HDIM 512
#define KDIM 1024          // FEAT + HDIM
#define NCOLS 3072         // 512 px + 2560 gates

__device__ __forceinline__ float sigmoidf_(float x) {
    return 1.0f / (1.0f + expf(-x));
}

__global__ __launch_bounds__(256) void prep_kernel(
    const float* __restrict__ px_w, const float* __restrict__ px_b,
    const float* __restrict__ iofux_w, const float* __restrict__ iofux_b,
    const float* __restrict__ iofuh_w, const float* __restrict__ iofuh_b,
    float* __restrict__ Bt, float* __restrict__ biasC)
{
    int idx = blockIdx.x * 256 + threadIdx.x;   // over KDIM*NCOLS
    if (idx < KDIM * NCOLS) {
        int k = idx / NCOLS;
        int c = idx - k * NCOLS;
        float v;
        if (c < 512) {
            v = (k < 512) ? px_w[c * 512 + k] : 0.0f;
        } else {
            int q = c - 512;
            v = (k < 512) ? iofux_w[q * 512 + k] : iofuh_w[q * 512 + (k - 512)];
        }
        Bt[idx] = v;
    }
    if (idx < NCOLS) {
        biasC[idx] = (idx < 512) ? px_b[idx] : (iofux_b[idx - 512] + iofuh_b[idx - 512]);
    }
}

// One level of the tree. Grid: (ceil(n/32), 8). Block 256 threads.
// Block computes nodes [nm0, nm0+32) x unit-chunk ub (64 units), i.e. the 6
// column chunks {px, i, o, f, u, r} at cols ch*512 + ub*64 + c, then fuses the
// LSTM gating epilogue, writing c_all and h_all (= d_out) for this level.
__global__ __launch_bounds__(256) void level_kernel(
    const float* __restrict__ feats_all,   // N_NODES x 512
    const float* __restrict__ Bt,          // 1024 x 3072
    const float* __restrict__ biasC,       // 3072
    float* __restrict__ c_all,             // N_NODES x 512
    float* __restrict__ h_all,             // N_NODES x 512 (== d_out)
    int level)
{
    const int n      = 1 << level;
    const int start  = n - 1;
    const int startp = (n >> 1) - 1;       // prev-level start (level>0)
    const int ub     = blockIdx.y;         // unit chunk 0..7
    const int nm0    = blockIdx.x * 32;    // first node of tile
    const int t      = threadIdx.x;
    const int c      = t & 63;             // col within chunk
    const int slot   = t >> 6;             // 0..3, 8 nodes each
    const int colbase = ub * 64;

    __shared__ float As[16][32];           // [k][m]
    __shared__ float Bs[16][384];          // [k][ch*64 + c]

    float acc[8][6];
#pragma unroll
    for (int a = 0; a < 8; ++a)
#pragma unroll
        for (int b = 0; b < 6; ++b) acc[a][b] = 0.0f;

    for (int k0 = 0; k0 < KDIM; k0 += 16) {
        __syncthreads();
        // ---- stage A tile: As[k][m] = A[nm0+m][k0+k]; A = [feats | parent_h]
        {
            int m  = t >> 3;               // 0..31
            int kk = (t & 7) << 1;         // 0,2,..,14
            int j  = nm0 + m;
            float2 v = make_float2(0.0f, 0.0f);
            if (j < n) {
                int kg = k0 + kk;
                if (kg < 512) {
                    v = *(const float2*)(feats_all + (size_t)(start + j) * 512 + kg);
                } else if (level > 0) {
                    v = *(const float2*)(h_all + (size_t)(startp + (j >> 1)) * 512 + (kg - 512));
                }
            }
            As[kk][m]     = v.x;
            As[kk + 1][m] = v.y;
        }
        // ---- stage B tile: Bs[k][ch*64+c] = Bt[(k0+k)*3072 + ch*512 + colbase + c]
        {
#pragma unroll
            for (int pass = 0; pass < 6; ++pass) {
                int f   = pass * 256 + t;      // 0..1535 float4 groups
                int kk  = f / 96;
                int g   = f - kk * 96;         // 0..95
                int ch  = g >> 4;              // 0..5
                int ci  = (g & 15) << 2;       // 0..60
                float4 v = *(const float4*)(Bt + (size_t)(k0 + kk) * NCOLS + ch * 512 + colbase + ci);
                *(float4*)&Bs[kk][ch * 64 + ci] = v;
            }
        }
        __syncthreads();
        // ---- compute
#pragma unroll
        for (int kk = 0; kk < 16; ++kk) {
            float4 a0 = *(const float4*)&As[kk][slot * 8];
            float4 a1 = *(const float4*)&As[kk][slot * 8 + 4];
            float bv[6];
#pragma unroll
            for (int ch = 0; ch < 6; ++ch) bv[ch] = Bs[kk][ch * 64 + c];
            float av[8] = {a0.x, a0.y, a0.z, a0.w, a1.x, a1.y, a1.z, a1.w};
#pragma unroll
            for (int nj = 0; nj < 8; ++nj)
#pragma unroll
                for (int ch = 0; ch < 6; ++ch)
                    acc[nj][ch] = fmaf(av[nj], bv[ch], acc[nj][ch]);
        }
    }

    // ---- epilogue: gating
    float bb[6];
#pragma unroll
    for (int ch = 0; ch < 6; ++ch) bb[ch] = biasC[ch * 512 + colbase + c];

#pragma unroll
    for (int nj = 0; nj < 8; ++nj) {
        int j = nm0 + slot * 8 + nj;
        if (j < n) {
            float px = acc[nj][0] + bb[0];
            float gi = sigmoidf_(acc[nj][1] + bb[1]);
            float go = sigmoidf_(acc[nj][2] + bb[2]);
            float gf = sigmoidf_(acc[nj][3] + bb[3]);
            float gu = tanhf(acc[nj][4] + bb[4]);
            float gr = sigmoidf_(acc[nj][5] + bb[5]);
            float pc = (level > 0) ? c_all[(size_t)(startp + (j >> 1)) * 512 + colbase + c] : 0.0f;
            float cc = gi * gu + gf * pc;
            float hh = go * tanhf(cc);
            float hf = gr * hh + (1.0f - gr) * px;
            size_t o = (size_t)(start + j) * 512 + colbase + c;
            c_all[o] = cc;
            h_all[o] = hf;
        }
    }
}

extern "C" void kernel_launch(void* const* d_in, const int* in_sizes, int n_in,
                              void* d_out, int out_size, void* d_ws, size_t ws_size,
                              hipStream_t stream)
{
    const float* features = (const float*)d_in[0];
    const float* px_w     = (const float*)d_in[1];
    const float* px_b     = (const float*)d_in[2];
    const float* iofux_w  = (const float*)d_in[3];
    const float* iofux_b  = (const float*)d_in[4];
    const float* iofuh_w  = (const float*)d_in[5];
    const float* iofuh_b  = (const float*)d_in[6];
    float* out = (float*)d_out;

    float* c_all = (float*)d_ws;
    float* Bt    = c_all + (size_t)N_NODES * 512;
    float* biasC = Bt + (size_t)KDIM * NCOLS;

    {
        int total = KDIM * NCOLS;
        prep_kernel<<<(total + 255) / 256, 256, 0, stream>>>(
            px_w, px_b, iofux_w, iofux_b, iofuh_w, iofuh_b, Bt, biasC);
    }

    for (int d = 0; d < DEPTH; ++d) {
        int n = 1 << d;
        dim3 grid((n + 31) / 32, 8);
        level_kernel<<<grid, 256, 0, stream>>>(features, Bt, biasC, c_all, out, d);
    }
}

// Round 2
// 2081.154 us; speedup vs baseline: 6.4650x; 6.4650x over previous
//
#include <hip/hip_runtime.h>
#include <cstddef>
#include <cstdint>

// BiTreeLSTM forward, bf16-MFMA version.
// DEPTH=17, N_NODES=131071, FEAT=H=512, K=1024 (feats | parent_h).
//
// Combined weight matrix Bt (bf16), stored col-major [col][k], k in [0,1024):
//   col = (u>>4)*96 + ch*16 + (u&15),  ch: 0=px,1=i,2=o,3=f,4=u,5=r, u in [0,512)
//   px chunk rows k>=512 are zero. A 96-col block tile = 16 units x all 6 chunks,
//   so the LSTM gating epilogue is fully in-register per lane.
//
// ws layout:
//   c_all     : N_NODES*512 fp32   (268.4 MB)
//   feats_bf  : N_NODES*512 bf16   (134.2 MB)
//   h_bf      : N_NODES*512 bf16   (134.2 MB)
//   Bt        : 3072*1024  bf16    (6.3 MB)
//   biasC     : 3072 fp32
// total ~543 MB.

#define DEPTH   17
#define N_NODES ((1 << DEPTH) - 1)
#define HD      512
#define KD      1024
#define NC      3072
#define LP      40      // LDS row stride in shorts (32 data + 8 pad -> 2-way free)

typedef __attribute__((ext_vector_type(8))) short short8;
typedef __attribute__((ext_vector_type(4))) float f32x4;

__device__ __forceinline__ unsigned short f2bf(float x) {
    unsigned u = __builtin_bit_cast(unsigned, x);
    u += 0x7FFFu + ((u >> 16) & 1u);          // round-to-nearest-even
    return (unsigned short)(u >> 16);
}
__device__ __forceinline__ float sig(float x) { return 1.0f / (1.0f + __expf(-x)); }

__global__ __launch_bounds__(256) void prep_weights(
    const float* __restrict__ px_w, const float* __restrict__ px_b,
    const float* __restrict__ iofux_w, const float* __restrict__ iofux_b,
    const float* __restrict__ iofuh_w, const float* __restrict__ iofuh_b,
    short* __restrict__ Bt, float* __restrict__ biasC)
{
    int idx = blockIdx.x * 256 + threadIdx.x;       // idx = col*1024 + k
    if (idx < NC * KD) {
        int col = idx >> 10, k = idx & 1023;
        int g = col / 96, rem = col - g * 96;
        int ch = rem >> 4;
        int u = g * 16 + (rem & 15);
        float v;
        if (ch == 0) {
            v = (k < 512) ? px_w[u * 512 + k] : 0.0f;
        } else {
            int q = (ch - 1) * 512 + u;
            v = (k < 512) ? iofux_w[q * 512 + k] : iofuh_w[q * 512 + (k - 512)];
        }
        Bt[idx] = (short)f2bf(v);
    }
    if (idx < NC) {
        int g = idx / 96, rem = idx - g * 96;
        int ch = rem >> 4;
        int u = g * 16 + (rem & 15);
        float b;
        if (ch == 0) b = px_b[u];
        else {
            int q = (ch - 1) * 512 + u;
            b = iofux_b[q] + iofuh_b[q];
        }
        biasC[idx] = b;
    }
}

__global__ __launch_bounds__(256) void conv_feats(
    const float* __restrict__ f, unsigned* __restrict__ o, int n4)
{
    int i = blockIdx.x * 256 + threadIdx.x;
    if (i < n4) {
        float4 v = ((const float4*)f)[i];
        unsigned lo = (unsigned)f2bf(v.x) | ((unsigned)f2bf(v.y) << 16);
        unsigned hi = (unsigned)f2bf(v.z) | ((unsigned)f2bf(v.w) << 16);
        ((uint2*)o)[i] = make_uint2(lo, hi);
    }
}

// One tree level. Grid: (ceil(n/128), 32). Block 256 = 4 waves.
// Block tile: 128 nodes x 96 cols (16 units x 6 chunks). Wave: 32 nodes x 96.
__global__ __launch_bounds__(256) void level_mfma(
    const short* __restrict__ feats_bf,   // N_NODES x 512 bf16
    short* __restrict__ h_bf,             // N_NODES x 512 bf16
    const short* __restrict__ Bt,         // 3072 x 1024 bf16 (col-major)
    const float* __restrict__ biasC,      // 3072
    float* __restrict__ c_all,            // N_NODES x 512 fp32
    float* __restrict__ out,              // N_NODES x 512 fp32 (d_out)
    int level)
{
    const int n      = 1 << level;
    const int start  = n - 1;
    const int startp = (n >> 1) - 1;
    const int mb     = blockIdx.x * 128;
    const int ub     = blockIdx.y;        // 16-unit group, 0..31
    const int t      = threadIdx.x;
    const int wave   = t >> 6;
    const int lane   = t & 63;

    __shared__ short As[128 * LP];
    __shared__ short Bs[96 * LP];

    f32x4 acc[2][6];
#pragma unroll
    for (int a = 0; a < 2; ++a)
#pragma unroll
        for (int b = 0; b < 6; ++b) acc[a][b] = (f32x4)(0.0f);

    // A staging: 2 threads per row, 32B (16 bf16) each
    const int rowA  = t >> 1;
    const int segA  = t & 1;
    const int nodeA = mb + rowA;
    const int nodeAc = (nodeA < n) ? nodeA : (n - 1);
    const short* aF = feats_bf + (size_t)(start + nodeAc) * HD + segA * 16;
    const short* aH = h_bf + (size_t)(startp + (nodeAc >> 1)) * HD + segA * 16;
    // B staging: threads 0..191, 2 per col
    const bool  bact = t < 192;
    const int   colB = t >> 1;
    const int   segB = t & 1;
    const short* bG = Bt + ((size_t)(ub * 96 + colB) << 10) + segB * 16;

    const int kend = (level == 0) ? 512 : KD;

    for (int k0 = 0; k0 < kend; k0 += 32) {
        const short* ap = (k0 < 512) ? (aF + k0) : (aH + (k0 - 512));
        int4 av0 = *(const int4*)(ap);
        int4 av1 = *(const int4*)(ap + 8);
        int4 bv0, bv1;
        if (bact) {
            bv0 = *(const int4*)(bG + k0);
            bv1 = *(const int4*)(bG + k0 + 8);
        }
        __syncthreads();   // previous tile's readers done
        *(int4*)&As[rowA * LP + segA * 16]     = av0;
        *(int4*)&As[rowA * LP + segA * 16 + 8] = av1;
        if (bact) {
            *(int4*)&Bs[colB * LP + segB * 16]     = bv0;
            *(int4*)&Bs[colB * LP + segB * 16 + 8] = bv1;
        }
        __syncthreads();

        const int fb = (lane & 15) * LP + (lane >> 4) * 8;
        short8 a0 = *(const short8*)&As[(wave * 32) * LP + fb];
        short8 a1 = *(const short8*)&As[(wave * 32 + 16) * LP + fb];
#pragma unroll
        for (int ch = 0; ch < 6; ++ch) {
            short8 bf = *(const short8*)&Bs[(ch * 16) * LP + fb];
            acc[0][ch] = __builtin_amdgcn_mfma_f32_16x16x32_bf16(a0, bf, acc[0][ch], 0, 0, 0);
            acc[1][ch] = __builtin_amdgcn_mfma_f32_16x16x32_bf16(a1, bf, acc[1][ch], 0, 0, 0);
        }
    }

    // ---- fused gating epilogue (C/D layout: col=lane&15, row=(lane>>4)*4+reg)
    const int l15 = lane & 15, qr = lane >> 4;
    const float b0 = biasC[ub * 96 +       l15];
    const float b1 = biasC[ub * 96 + 16  + l15];
    const float b2 = biasC[ub * 96 + 32  + l15];
    const float b3 = biasC[ub * 96 + 48  + l15];
    const float b4 = biasC[ub * 96 + 64  + l15];
    const float b5 = biasC[ub * 96 + 80  + l15];
    const int uglob = ub * 16 + l15;

#pragma unroll
    for (int mt = 0; mt < 2; ++mt) {
        int j0 = mb + wave * 32 + mt * 16 + qr * 4;
#pragma unroll
        for (int r = 0; r < 4; ++r) {
            int j = j0 + r;
            if (j < n) {
                float px = acc[mt][0][r] + b0;
                float gi = sig(acc[mt][1][r] + b1);
                float go = sig(acc[mt][2][r] + b2);
                float gf = sig(acc[mt][3][r] + b3);
                float gu = tanhf(acc[mt][4][r] + b4);
                float gr = sig(acc[mt][5][r] + b5);
                float pc = (level > 0)
                    ? c_all[(size_t)(startp + (j >> 1)) * HD + uglob] : 0.0f;
                float cc = gi * gu + gf * pc;
                float hh = go * tanhf(cc);
                float hf = gr * hh + (1.0f - gr) * px;
                size_t off = (size_t)(start + j) * HD + uglob;
                c_all[off] = cc;
                out[off]   = hf;
                h_bf[off]  = (short)f2bf(hf);
            }
        }
    }
}

extern "C" void kernel_launch(void* const* d_in, const int* in_sizes, int n_in,
                              void* d_out, int out_size, void* d_ws, size_t ws_size,
                              hipStream_t stream)
{
    const float* features = (const float*)d_in[0];
    const float* px_w     = (const float*)d_in[1];
    const float* px_b     = (const float*)d_in[2];
    const float* iofux_w  = (const float*)d_in[3];
    const float* iofux_b  = (const float*)d_in[4];
    const float* iofuh_w  = (const float*)d_in[5];
    const float* iofuh_b  = (const float*)d_in[6];
    float* out = (float*)d_out;

    float* c_all    = (float*)d_ws;
    short* feats_bf = (short*)(c_all + (size_t)N_NODES * HD);
    short* h_bf     = feats_bf + (size_t)N_NODES * HD;
    short* Bt       = h_bf + (size_t)N_NODES * HD;
    float* biasC    = (float*)(Bt + (size_t)NC * KD);

    {
        int total = NC * KD;
        prep_weights<<<(total + 255) / 256, 256, 0, stream>>>(
            px_w, px_b, iofux_w, iofux_b, iofuh_w, iofuh_b, Bt, biasC);
    }
    {
        int n4 = (N_NODES * HD) / 4;   // 512 divisible by 4
        conv_feats<<<(n4 + 255) / 256, 256, 0, stream>>>(
            features, (unsigned*)feats_bf, n4);
    }
    for (int d = 0; d < DEPTH; ++d) {
        int n = 1 << d;
        dim3 grid((n + 127) / 128, 32);
        level_mfma<<<grid, 256, 0, stream>>>(
            feats_bf, h_bf, Bt, biasC, c_all, out, d);
    }
}